// Round 5
// baseline (792.944 us; speedup 1.0000x reference)
//
#include <hip/hip_runtime.h>
#include <hip/hip_bf16.h>

#define B_ 8
#define C_ 256
#define H_ 64
#define W_ 64
#define HW_ 4096
#define E_ 32
#define K_ 8192
#define N_ 32768          // B*H*W
#define NCHUNK 8
#define KC_ (K_ / NCHUNK) // 1024
#define P_ 4              // pixels per thread in score kernel

#define DECAY_ 0.99f
#define OMD_   0.01f
#define EPS_   1e-5f
#define BETA_  0.25f

// ---- output layout (fp32 elements, concatenated in reference return order) ----
#define O_ZQ   0          // [B,E,H,W] 1048576
#define O_IDX  1048576    // [B,H,W]   32768
#define O_QL   1081344    // scalar    1
#define O_NEMB 1081345    // [K,E]     262144
#define O_NCS  1343489    // [K]       8192
#define O_NW   1351681    // [K,E]     262144

// ---- workspace layout (float offsets into d_ws); total 2.52 MB ----
#define WS_EN   0u        // K*E fp32 normalized embedding   [0,      262144)
#define WS_PACK 262144u   // N u64 packed (score,idx), zeroed [262144, 327680)
#define WS_CNT  327680u   // K counts (zeroed)
#define WS_DW   335872u   // K*E dw (zeroed)
#define WS_SCAL 598016u   // [0]=n sum, [1]=qloss sq sum (zeroed)
#define WS_IDX  598018u   // N final indices (int)
// memset span: WS_PACK .. WS_IDX = 335874 floats

// monotone float -> ordered uint map
__device__ __forceinline__ unsigned ford(float f) {
    unsigned u = __float_as_uint(f);
    return (u & 0x80000000u) ? ~u : (u | 0x80000000u);
}

// ---------------- K0: normalize embedding rows (fp32) ----------------
__global__ __launch_bounds__(256) void k_norm_emb(const float* __restrict__ emb,
                                                  float* __restrict__ en) {
    int k = blockIdx.x * 256 + threadIdx.x;
    if (k >= K_) return;
    const float4* r = (const float4*)(emb + (size_t)k * E_);
    float4 v[8];
    float ss = 0.f;
#pragma unroll
    for (int i = 0; i < 8; i++) {
        v[i] = r[i];
        ss += v[i].x * v[i].x + v[i].y * v[i].y + v[i].z * v[i].z + v[i].w * v[i].w;
    }
    float inv = 1.0f / fmaxf(sqrtf(ss), 1e-12f);
    float4* o = (float4*)(en + (size_t)k * E_);
#pragma unroll
    for (int i = 0; i < 8; i++) {
        o[i] = make_float4(v[i].x * inv, v[i].y * inv, v[i].z * inv, v[i].w * inv);
    }
}

// ---------------- K1: fused z-GEMM (P=4 pixels/thread) + scores + argmax ----------------
__global__ __launch_bounds__(256) void k_score4(const float* __restrict__ x,
                                                const float* __restrict__ Wq,
                                                const float* __restrict__ bq,
                                                const float* __restrict__ en,
                                                unsigned long long* __restrict__ pack) {
    __shared__ float lds[C_ * E_];   // 32 KB: WqT first, then en tiles
    int tid = threadIdx.x;
    int nb  = blockIdx.x * (256 * P_) + tid;   // pixel p = nb + p*256, all same b

    // stage WqT [c][e]
#pragma unroll
    for (int i = 0; i < (C_ * E_) / 256; i++) {
        int g = i * 256 + tid;       // g = e*C_ + c  (Wq is [E,C])
        int e = g >> 8;
        int c = g & (C_ - 1);
        lds[c * E_ + e] = Wq[g];
    }
    __syncthreads();

    int b  = nb >> 12;
    int hw = nb & (HW_ - 1);
    const float* xp = x + (size_t)b * C_ * HW_ + hw;

    float4 acc[P_][8];
#pragma unroll
    for (int p = 0; p < P_; p++)
#pragma unroll
        for (int i = 0; i < 8; i++) acc[p][i] = make_float4(0.f, 0.f, 0.f, 0.f);

    const float4* w4 = (const float4*)lds;
#pragma unroll 2
    for (int c = 0; c < C_; c++) {
        float xv[P_];
#pragma unroll
        for (int p = 0; p < P_; p++) xv[p] = xp[(size_t)c * HW_ + p * 256];
#pragma unroll
        for (int i = 0; i < 8; i++) {
            float4 w = w4[c * 8 + i];
#pragma unroll
            for (int p = 0; p < P_; p++) {
                acc[p][i].x += xv[p] * w.x; acc[p][i].y += xv[p] * w.y;
                acc[p][i].z += xv[p] * w.z; acc[p][i].w += xv[p] * w.w;
            }
        }
    }
#pragma unroll
    for (int p = 0; p < P_; p++)
#pragma unroll
        for (int i = 0; i < 8; i++) {
            acc[p][i].x += bq[i * 4 + 0];
            acc[p][i].y += bq[i * 4 + 1];
            acc[p][i].z += bq[i * 4 + 2];
            acc[p][i].w += bq[i * 4 + 3];
        }
    __syncthreads();   // done with WqT; reuse LDS for en tiles

    int kbase = blockIdx.y * KC_;
    float best[P_];
    int   bidx[P_];
#pragma unroll
    for (int p = 0; p < P_; p++) { best[p] = -3.0e38f; bidx[p] = 0; }

    for (int t = 0; t < KC_ / 256; t++) {
        const float4* src = (const float4*)en + (size_t)(kbase + t * 256) * (E_ / 4);
        float4* dst = (float4*)lds;
#pragma unroll
        for (int i = 0; i < 8; i++) dst[i * 256 + tid] = src[i * 256 + tid];
        __syncthreads();

        for (int r = 0; r < 256; r++) {
            const float4* er = (const float4*)(lds + r * E_);
            float4 e4[8];
#pragma unroll
            for (int i = 0; i < 8; i++) e4[i] = er[i];
            int k = kbase + t * 256 + r;
#pragma unroll
            for (int p = 0; p < P_; p++) {
                float sa = 0.f, sb = 0.f;
#pragma unroll
                for (int i = 0; i < 8; i += 2) {
                    sa += acc[p][i].x * e4[i].x;     sa += acc[p][i].y * e4[i].y;
                    sa += acc[p][i].z * e4[i].z;     sa += acc[p][i].w * e4[i].w;
                    sb += acc[p][i+1].x * e4[i+1].x; sb += acc[p][i+1].y * e4[i+1].y;
                    sb += acc[p][i+1].z * e4[i+1].z; sb += acc[p][i+1].w * e4[i+1].w;
                }
                float s = sa + sb;
                if (s > best[p]) { best[p] = s; bidx[p] = k; }  // strict >: first max wins
            }
        }
        __syncthreads();
    }
#pragma unroll
    for (int p = 0; p < P_; p++) {
        unsigned long long val =
            ((unsigned long long)ford(best[p]) << 32) | (unsigned)(K_ - 1 - bidx[p]);
        atomicMax(&pack[nb + p * 256], val);
    }
}

// ---------------- K2: unpack argmax ----------------
__global__ __launch_bounds__(256) void k_combine(const unsigned long long* __restrict__ pack,
                                                 int* __restrict__ idxs,
                                                 float* __restrict__ out_idx) {
    int n = blockIdx.x * 256 + threadIdx.x;
    if (n >= N_) return;
    unsigned long long v = pack[n];
    int bi = K_ - 1 - (int)(unsigned)(v & 0xffffffffu);
    idxs[n] = bi;
    out_idx[n] = (float)bi;
}

// Shared z-compute (P=1) for scatter kernel.
__device__ __forceinline__ void compute_z(const float* __restrict__ x,
                                          const float* __restrict__ Wq,
                                          const float* __restrict__ bq,
                                          float* lds, int tid, int n,
                                          float4 zr[8]) {
#pragma unroll
    for (int i = 0; i < (C_ * E_) / 256; i++) {
        int g = i * 256 + tid;
        int e = g >> 8;
        int c = g & (C_ - 1);
        lds[c * E_ + e] = Wq[g];
    }
    __syncthreads();

    int b  = n >> 12;
    int hw = n & (HW_ - 1);
    const float* xp = x + (size_t)b * C_ * HW_ + hw;

    float4 acc[8];
#pragma unroll
    for (int i = 0; i < 8; i++) acc[i] = make_float4(0.f, 0.f, 0.f, 0.f);

    const float4* w4 = (const float4*)lds;
#pragma unroll 4
    for (int c = 0; c < C_; c++) {
        float xv = xp[(size_t)c * HW_];
#pragma unroll
        for (int i = 0; i < 8; i++) {
            float4 w = w4[c * 8 + i];
            acc[i].x += xv * w.x; acc[i].y += xv * w.y;
            acc[i].z += xv * w.z; acc[i].w += xv * w.w;
        }
    }
#pragma unroll
    for (int i = 0; i < 8; i++) {
        acc[i].x += bq[i * 4 + 0];
        acc[i].y += bq[i * 4 + 1];
        acc[i].z += bq[i * 4 + 2];
        acc[i].w += bq[i * 4 + 3];
        zr[i] = acc[i];
    }
    __syncthreads();
}

// ---------------- K3: recompute z, gather z_q, qloss, scatter counts/dw ----------------
__global__ __launch_bounds__(256) void k_scatter(const float* __restrict__ x,
                                                 const float* __restrict__ Wq,
                                                 const float* __restrict__ bq,
                                                 const int* __restrict__ idxs,
                                                 const float* __restrict__ emb,
                                                 float* __restrict__ out_zq,
                                                 float* __restrict__ dw,
                                                 float* __restrict__ cnt,
                                                 float* __restrict__ scal) {
    __shared__ float lds[C_ * E_];
    int tid = threadIdx.x;
    int n   = blockIdx.x * 256 + tid;

    float4 zr[8];
    compute_z(x, Wq, bq, lds, tid, n, zr);
    const float* zf = (const float*)zr;

    int b   = n >> 12;
    int hw  = n & (HW_ - 1);
    int idx = idxs[n];
    idx = idx < 0 ? 0 : (idx > K_ - 1 ? K_ - 1 : idx);
    const float* er = emb + (size_t)idx * E_;
    float* o = out_zq + (size_t)b * E_ * HW_ + hw;

    float sq = 0.f;
#pragma unroll
    for (int e = 0; e < E_; e++) {
        float qf = er[e];
        float zv = zf[e];
        float d = qf - zv;
        sq += d * d;
        o[(size_t)e * HW_] = qf;
        atomicAdd(dw + (size_t)idx * E_ + e, zv);
    }
    atomicAdd(cnt + idx, 1.0f);

#pragma unroll
    for (int off = 32; off > 0; off >>= 1) sq += __shfl_down(sq, off);
    __shared__ float red[4];
    int lane = tid & 63, wid = tid >> 6;
    if (lane == 0) red[wid] = sq;
    __syncthreads();
    if (tid == 0) atomicAdd(scal + 1, red[0] + red[1] + red[2] + red[3]);
}

// ---------------- K4: EMA cluster size + n reduction ----------------
__global__ __launch_bounds__(256) void k_ema_cs(const float* __restrict__ cs,
                                                const float* __restrict__ cnt,
                                                float* __restrict__ out_ncs,
                                                float* __restrict__ scal) {
    int tid = threadIdx.x;
    int k = blockIdx.x * 256 + tid;
    float v = DECAY_ * cs[k] + OMD_ * cnt[k];
    out_ncs[k] = v;

    float s = v;
#pragma unroll
    for (int off = 32; off > 0; off >>= 1) s += __shfl_down(s, off);
    __shared__ float red[4];
    int lane = tid & 63, wid = tid >> 6;
    if (lane == 0) red[wid] = s;
    __syncthreads();
    if (tid == 0) atomicAdd(scal + 0, red[0] + red[1] + red[2] + red[3]);
}

// ---------------- K5: new_w + smoothed division + qloss write ----------------
__global__ __launch_bounds__(256) void k_final(const float* __restrict__ ew,
                                               const float* __restrict__ dw,
                                               const float* __restrict__ cs,
                                               const float* __restrict__ cnt,
                                               const float* __restrict__ scal,
                                               float* __restrict__ out_nw,
                                               float* __restrict__ out_nemb,
                                               float* __restrict__ out_ql) {
    int j = blockIdx.x * 256 + threadIdx.x;  // < K_*E_
    float v = DECAY_ * ew[j] + OMD_ * dw[j];     // new_w
    out_nw[j] = v;
    float nsum = scal[0];
    int k = j >> 5;
    float csk = DECAY_ * cs[k] + OMD_ * cnt[k];  // new_cs
    float denom = (csk + EPS_) / (nsum + (float)K_ * EPS_) * nsum;
    out_nemb[j] = v / denom;
    if (j == 0) {
        out_ql[0] = BETA_ * scal[1] / (float)(B_ * E_ * HW_);
    }
}

extern "C" void kernel_launch(void* const* d_in, const int* in_sizes, int n_in,
                              void* d_out, int out_size, void* d_ws, size_t ws_size,
                              hipStream_t stream) {
    const float* x   = (const float*)d_in[0];
    const float* Wq  = (const float*)d_in[1];
    const float* bq  = (const float*)d_in[2];
    const float* emb = (const float*)d_in[3];
    const float* cs  = (const float*)d_in[4];
    const float* ew  = (const float*)d_in[5];
    float* out = (float*)d_out;
    float* ws = (float*)d_ws;

    // zero PACK + CNT + DW + SCAL (contiguous span)
    hipMemsetAsync(ws + WS_PACK, 0, (size_t)(WS_IDX - WS_PACK) * sizeof(float), stream);

    k_norm_emb<<<K_ / 256, 256, 0, stream>>>(emb, ws + WS_EN);
    k_score4<<<dim3(N_ / (256 * P_), NCHUNK), 256, 0, stream>>>(
        x, Wq, bq, ws + WS_EN, (unsigned long long*)(ws + WS_PACK));
    k_combine<<<N_ / 256, 256, 0, stream>>>((const unsigned long long*)(ws + WS_PACK),
                                            (int*)(ws + WS_IDX), out + O_IDX);
    k_scatter<<<N_ / 256, 256, 0, stream>>>(x, Wq, bq, (const int*)(ws + WS_IDX), emb,
                                            out + O_ZQ, ws + WS_DW, ws + WS_CNT,
                                            ws + WS_SCAL);
    k_ema_cs<<<K_ / 256, 256, 0, stream>>>(cs, ws + WS_CNT, out + O_NCS, ws + WS_SCAL);
    k_final<<<(K_ * E_) / 256, 256, 0, stream>>>(ew, ws + WS_DW, cs, ws + WS_CNT,
                                                 ws + WS_SCAL, out + O_NW,
                                                 out + O_NEMB, out + O_QL);
}

// Round 8
// 488.376 us; speedup vs baseline: 1.6236x; 1.6236x over previous
//
#include <hip/hip_runtime.h>

#define B_ 8
#define C_ 256
#define HW_ 4096
#define E_ 32
#define K_ 8192
#define N_ 32768          // B*H*W

#define DECAY_ 0.99f
#define OMD_   0.01f
#define EPS_   1e-5f
#define BETA_  0.25f

// ---- output layout (fp32 elements, concatenated in reference return order) ----
#define O_ZQ   0          // [B,E,H,W] 1048576
#define O_IDX  1048576    // [B,H,W]   32768
#define O_QL   1081344    // scalar    1
#define O_NEMB 1081345    // [K,E]     262144
#define O_NCS  1343489    // [K]       8192
#define O_NW   1351681    // [K,E]     262144

// ---- workspace layout (float offsets into d_ws); high-water 794626 floats = 3.18 MB
// (round 4 proved 827394 floats safe)
// Each bf16 split plane: K*E shorts = 262144 bf16 = 131072 floats.
#define WS_EH   0u        // [0,      131072)
#define WS_EM   131072u   // [131072, 262144)
#define WS_EL   262144u   // [262144, 393216)
#define WS_P1   393216u   // N u64 packed best   [393216, 458752)
#define WS_P2   458752u   // N u64 packed second [458752, 524288)
#define WS_CNT  524288u   // K counts (zeroed)   [524288, 532480)
#define WS_DW   532480u   // K*E dw (zeroed)     [532480, 794624)
#define WS_SCAL 794624u   // [0]=n sum, [1]=qloss sq sum (zeroed)
// memset span: WS_CNT .. WS_SCAL+2 = 270338 floats

typedef float f32x4 __attribute__((ext_vector_type(4)));
typedef short s16x8 __attribute__((ext_vector_type(8)));
typedef unsigned long long u64;

// RNE float -> bf16 bits (finite inputs)
__device__ __forceinline__ unsigned short f2bf(float f) {
    unsigned u = __float_as_uint(f);
    u = u + 0x7fffu + ((u >> 16) & 1u);
    return (unsigned short)(u >> 16);
}
__device__ __forceinline__ float bf2f(unsigned short h) {
    return __uint_as_float(((unsigned)h) << 16);
}
// monotone float -> ordered uint
__device__ __forceinline__ unsigned ford(float f) {
    unsigned u = __float_as_uint(f);
    return (u & 0x80000000u) ? ~u : (u | 0x80000000u);
}

// ---------------- K0: normalize embedding rows + 3-way bf16 split ----------------
__global__ __launch_bounds__(256) void k_norm_split(const float* __restrict__ emb,
                                                    unsigned short* __restrict__ eh,
                                                    unsigned short* __restrict__ em,
                                                    unsigned short* __restrict__ el) {
    int k = blockIdx.x * 256 + threadIdx.x;
    if (k >= K_) return;
    const float4* r = (const float4*)(emb + (size_t)k * E_);
    float v[E_];
    float ss = 0.f;
#pragma unroll
    for (int i = 0; i < 8; i++) {
        float4 t = r[i];
        v[i*4+0] = t.x; v[i*4+1] = t.y; v[i*4+2] = t.z; v[i*4+3] = t.w;
        ss += t.x*t.x + t.y*t.y + t.z*t.z + t.w*t.w;
    }
    float inv = 1.0f / fmaxf(sqrtf(ss), 1e-12f);
    unsigned short h1a[E_], h2a[E_], h3a[E_];
#pragma unroll
    for (int e = 0; e < E_; e++) {
        float en = v[e] * inv;
        unsigned short h1 = f2bf(en);
        float r1 = en - bf2f(h1);
        unsigned short h2 = f2bf(r1);
        float r2 = r1 - bf2f(h2);
        unsigned short h3 = f2bf(r2);
        h1a[e] = h1; h2a[e] = h2; h3a[e] = h3;
    }
#pragma unroll
    for (int i = 0; i < 4; i++) {
        ((uint4*)(eh + (size_t)k * E_))[i] = ((uint4*)h1a)[i];
        ((uint4*)(em + (size_t)k * E_))[i] = ((uint4*)h2a)[i];
        ((uint4*)(el + (size_t)k * E_))[i] = ((uint4*)h3a)[i];
    }
}

// ---------------- K1: MFMA score + per-pixel top-2 ----------------
#define STCODES 128
#define NSTAGE (K_ / STCODES)   // 64

__global__ __launch_bounds__(256) void k_score_mfma(const float* __restrict__ x,
                                                    const float* __restrict__ Wq,
                                                    const float* __restrict__ bq,
                                                    const unsigned short* __restrict__ eh,
                                                    const unsigned short* __restrict__ em,
                                                    const unsigned short* __restrict__ el,
                                                    u64* __restrict__ p1out,
                                                    u64* __restrict__ p2out) {
    __shared__ __align__(16) char smem[40960];
    float* wqt  = (float*)smem;                 // 8192 floats (phase 1)
    float* zbuf = (float*)(smem + 32768);       // 2048 floats

    int tid  = threadIdx.x;
    int lane = tid & 63;
    int w    = tid >> 6;

    // ---- phase 1: z for the block's 64 pixels ----
#pragma unroll
    for (int i = 0; i < 32; i++) {
        int g = i * 256 + tid;        // g = e*256 + c  (Wq is [E,C])
        int e = g >> 8;
        int c = g & 255;
        wqt[c * E_ + e] = Wq[g];
    }
    __syncthreads();

    {
        int lp = tid & 63, eg = tid >> 6;
        int n0 = blockIdx.x * 64 + lp;
        int b  = n0 >> 12, hw = n0 & (HW_ - 1);
        const float* xp = x + (size_t)b * C_ * HW_ + hw;
        float a[8];
#pragma unroll
        for (int j = 0; j < 8; j++) a[j] = 0.f;
#pragma unroll 4
        for (int c = 0; c < C_; c++) {
            float xv = xp[(size_t)c * HW_];
            const float4* wr = (const float4*)(wqt + c * E_ + eg * 8);
            float4 w0 = wr[0], w1 = wr[1];
            a[0] += xv * w0.x; a[1] += xv * w0.y; a[2] += xv * w0.z; a[3] += xv * w0.w;
            a[4] += xv * w1.x; a[5] += xv * w1.y; a[6] += xv * w1.z; a[7] += xv * w1.w;
        }
        float4* zo = (float4*)(zbuf + lp * E_ + eg * 8);
        float4 o0 = make_float4(a[0] + bq[eg*8+0], a[1] + bq[eg*8+1],
                                a[2] + bq[eg*8+2], a[3] + bq[eg*8+3]);
        float4 o1 = make_float4(a[4] + bq[eg*8+4], a[5] + bq[eg*8+5],
                                a[6] + bq[eg*8+6], a[7] + bq[eg*8+7]);
        zo[0] = o0; zo[1] = o1;
    }
    __syncthreads();

    // ---- A fragments: z 3-way bf16 split. A[m=lane&15][k=(lane>>4)*8+j] ----
    s16x8 a1, a2, a3;
    {
        int ploc = w * 16 + (lane & 15);
        int e0   = (lane >> 4) * 8;
#pragma unroll
        for (int j = 0; j < 8; j++) {
            float zv = zbuf[ploc * E_ + e0 + j];
            unsigned short h1 = f2bf(zv);
            float r1 = zv - bf2f(h1);
            unsigned short h2 = f2bf(r1);
            float r2 = r1 - bf2f(h2);
            unsigned short h3 = f2bf(r2);
            a1[j] = (short)h1; a2[j] = (short)h2; a3[j] = (short)h3;
        }
    }

    float b1s[4], b2s[4];
    int   i1s[4], i2s[4];
#pragma unroll
    for (int j = 0; j < 4; j++) {
        b1s[j] = -3.0e38f; b2s[j] = -3.0e38f; i1s[j] = 0; i2s[j] = 1;
    }
    f32x4 zero4 = {0.f, 0.f, 0.f, 0.f};

    const float4* esrc0 = (const float4*)eh;
    const float4* esrc1 = (const float4*)em;
    const float4* esrc2 = (const float4*)el;
    float4* lds4 = (float4*)smem;

    for (int st = 0; st < NSTAGE; st++) {
        // stage 3 splits x 128 codes x 64B, frag-swizzled:
        // dest chunk (tile ct)*64 + q*16 + (c&15)  <-  (code c, quad q)
#pragma unroll
        for (int i = 0; i < 6; i++) {
            int g  = i * 256 + tid;
            int sp = g >> 9;
            int gc = g & 511;
            int c  = gc >> 2;
            int q  = gc & 3;
            const float4* sb = (sp == 0) ? esrc0 : ((sp == 1) ? esrc1 : esrc2);
            float4 v = sb[(size_t)(st * STCODES + c) * 4 + q];
            lds4[sp * 512 + (c >> 4) * 64 + q * 16 + (c & 15)] = v;
        }
        __syncthreads();

#pragma unroll
        for (int ct = 0; ct < 8; ct++) {
            s16x8 b1 = ((const s16x8*)(smem +          ct * 1024))[lane];
            s16x8 b2 = ((const s16x8*)(smem +  8192 +  ct * 1024))[lane];
            s16x8 b3 = ((const s16x8*)(smem + 16384 +  ct * 1024))[lane];
            f32x4 acc = __builtin_amdgcn_mfma_f32_16x16x32_bf16(a1, b1, zero4, 0, 0, 0);
            acc = __builtin_amdgcn_mfma_f32_16x16x32_bf16(a1, b2, acc, 0, 0, 0);
            acc = __builtin_amdgcn_mfma_f32_16x16x32_bf16(a2, b1, acc, 0, 0, 0);
            acc = __builtin_amdgcn_mfma_f32_16x16x32_bf16(a1, b3, acc, 0, 0, 0);
            acc = __builtin_amdgcn_mfma_f32_16x16x32_bf16(a2, b2, acc, 0, 0, 0);
            acc = __builtin_amdgcn_mfma_f32_16x16x32_bf16(a3, b1, acc, 0, 0, 0);
            int k = st * STCODES + ct * 16 + (lane & 15);
#pragma unroll
            for (int j = 0; j < 4; j++) {
                float s = acc[j];
                if (s > b1s[j]) {
                    b2s[j] = b1s[j]; i2s[j] = i1s[j];
                    b1s[j] = s;      i1s[j] = k;
                } else if (s > b2s[j]) {
                    b2s[j] = s; i2s[j] = k;
                }
            }
        }
        __syncthreads();
    }

    // ---- butterfly top-2 merge across the 16-lane code groups ----
    u64 pk1[4], pk2[4];
#pragma unroll
    for (int j = 0; j < 4; j++) {
        pk1[j] = ((u64)ford(b1s[j]) << 32) | (unsigned)(K_ - 1 - i1s[j]);
        pk2[j] = ((u64)ford(b2s[j]) << 32) | (unsigned)(K_ - 1 - i2s[j]);
    }
#pragma unroll
    for (int off = 1; off < 16; off <<= 1) {
#pragma unroll
        for (int j = 0; j < 4; j++) {
            u64 o1 = __shfl_xor(pk1[j], off, 64);
            u64 o2 = __shfl_xor(pk2[j], off, 64);
            u64 lo = pk1[j] < o1 ? pk1[j] : o1;
            pk1[j] = pk1[j] > o1 ? pk1[j] : o1;
            u64 hi2 = pk2[j] > o2 ? pk2[j] : o2;
            pk2[j] = lo > hi2 ? lo : hi2;
        }
    }
    if ((lane & 15) == 0) {
        int rowbase = blockIdx.x * 64 + w * 16 + (lane >> 4) * 4;
#pragma unroll
        for (int j = 0; j < 4; j++) {
            p1out[rowbase + j] = pk1[j];
            p2out[rowbase + j] = pk2[j];
        }
    }
}

// exact round-4-order rescore of one candidate code against z[32] (LDS)
__device__ __forceinline__ float rescore(const float* __restrict__ emb, int k,
                                         const float* zrow) {
    const float4* r = (const float4*)(emb + (size_t)k * E_);
    float4 v[8];
    float ss = 0.f;
#pragma unroll
    for (int i = 0; i < 8; i++) {
        v[i] = r[i];
        ss += v[i].x * v[i].x + v[i].y * v[i].y + v[i].z * v[i].z + v[i].w * v[i].w;
    }
    float inv = 1.0f / fmaxf(sqrtf(ss), 1e-12f);
    const float4* zp = (const float4*)zrow;
    float sx = 0.f, sy = 0.f, sz = 0.f, sw = 0.f;
#pragma unroll
    for (int i = 0; i < 8; i++) {
        float4 e4 = make_float4(v[i].x * inv, v[i].y * inv, v[i].z * inv, v[i].w * inv);
        float4 zr = zp[i];
        sx += zr.x * e4.x; sy += zr.y * e4.y;
        sz += zr.z * e4.z; sw += zr.w * e4.w;
    }
    return (sx + sy) + (sz + sw);
}

// ---------------- K2: recompute z, rescore top-2, gather/scatter ----------------
__global__ __launch_bounds__(256) void k_scatter(const float* __restrict__ x,
                                                 const float* __restrict__ Wq,
                                                 const float* __restrict__ bq,
                                                 const u64* __restrict__ p1,
                                                 const u64* __restrict__ p2,
                                                 const float* __restrict__ emb,
                                                 float* __restrict__ out_zq,
                                                 float* __restrict__ out_idx,
                                                 float* __restrict__ dw,
                                                 float* __restrict__ cnt,
                                                 float* __restrict__ scal) {
    __shared__ float wqt[C_ * E_];     // 32 KB
    __shared__ float zbuf[64 * E_];    // 8 KB
    __shared__ int   idxs_s[64];
    int tid = threadIdx.x;
#pragma unroll
    for (int i = 0; i < 32; i++) {
        int g = i * 256 + tid;
        int e = g >> 8;
        int c = g & 255;
        wqt[c * E_ + e] = Wq[g];
    }
    __syncthreads();

    int lp = tid & 63, eg = tid >> 6;
    int n  = blockIdx.x * 64 + lp;
    int b  = n >> 12, hw = n & (HW_ - 1);
    const float* xp = x + (size_t)b * C_ * HW_ + hw;

    float a[8];
#pragma unroll
    for (int j = 0; j < 8; j++) a[j] = 0.f;
#pragma unroll 4
    for (int c = 0; c < C_; c++) {
        float xv = xp[(size_t)c * HW_];
        const float4* wr = (const float4*)(wqt + c * E_ + eg * 8);
        float4 w0 = wr[0], w1 = wr[1];
        a[0] += xv * w0.x; a[1] += xv * w0.y; a[2] += xv * w0.z; a[3] += xv * w0.w;
        a[4] += xv * w1.x; a[5] += xv * w1.y; a[6] += xv * w1.z; a[7] += xv * w1.w;
    }
#pragma unroll
    for (int j = 0; j < 8; j++) a[j] += bq[eg * 8 + j];
    // publish z to zbuf for the rescore threads
#pragma unroll
    for (int j = 0; j < 8; j++) zbuf[lp * E_ + eg * 8 + j] = a[j];
    __syncthreads();

    if (tid < 64) {
        int nn = blockIdx.x * 64 + tid;
        u64 q1 = p1[nn], q2 = p2[nn];
        int k1 = K_ - 1 - (int)(unsigned)(q1 & 0xffffffffu);
        int k2 = K_ - 1 - (int)(unsigned)(q2 & 0xffffffffu);
        k1 = k1 < 0 ? 0 : (k1 > K_ - 1 ? K_ - 1 : k1);
        k2 = k2 < 0 ? 0 : (k2 > K_ - 1 ? K_ - 1 : k2);
        int ka = k1 < k2 ? k1 : k2;
        int kb = k1 < k2 ? k2 : k1;
        float sa = rescore(emb, ka, zbuf + tid * E_);
        float sb = rescore(emb, kb, zbuf + tid * E_);
        int idx = (sb > sa) ? kb : ka;   // ascending-k strict > (first max wins)
        idxs_s[tid] = idx;
        out_idx[nn] = (float)idx;
    }
    __syncthreads();

    int idx = idxs_s[lp];
    const float* er = emb + (size_t)idx * E_ + eg * 8;
    float* o = out_zq + (size_t)b * E_ * HW_ + (size_t)(eg * 8) * HW_ + hw;

    float sq = 0.f;
#pragma unroll
    for (int j = 0; j < 8; j++) {
        float zv = a[j];
        float qf = er[j];
        float d = qf - zv;
        sq += d * d;
        o[(size_t)j * HW_] = qf;
        atomicAdd(dw + (size_t)idx * E_ + eg * 8 + j, zv);
    }
    if (eg == 0) atomicAdd(cnt + idx, 1.0f);

#pragma unroll
    for (int off = 32; off > 0; off >>= 1) sq += __shfl_down(sq, off);
    __shared__ float red[4];
    int lane = tid & 63, wid = tid >> 6;
    if (lane == 0) red[wid] = sq;
    __syncthreads();
    if (tid == 0) atomicAdd(scal + 1, red[0] + red[1] + red[2] + red[3]);
}

// ---------------- K3: EMA cluster size + n reduction ----------------
__global__ __launch_bounds__(256) void k_ema_cs(const float* __restrict__ cs,
                                                const float* __restrict__ cnt,
                                                float* __restrict__ out_ncs,
                                                float* __restrict__ scal) {
    int tid = threadIdx.x;
    int k = blockIdx.x * 256 + tid;
    float v = DECAY_ * cs[k] + OMD_ * cnt[k];
    out_ncs[k] = v;

    float s = v;
#pragma unroll
    for (int off = 32; off > 0; off >>= 1) s += __shfl_down(s, off);
    __shared__ float red[4];
    int lane = tid & 63, wid = tid >> 6;
    if (lane == 0) red[wid] = s;
    __syncthreads();
    if (tid == 0) atomicAdd(scal + 0, red[0] + red[1] + red[2] + red[3]);
}

// ---------------- K4: new_w + smoothed division + qloss ----------------
__global__ __launch_bounds__(256) void k_final(const float* __restrict__ ew,
                                               const float* __restrict__ dw,
                                               const float* __restrict__ cs,
                                               const float* __restrict__ cnt,
                                               const float* __restrict__ scal,
                                               float* __restrict__ out_nw,
                                               float* __restrict__ out_nemb,
                                               float* __restrict__ out_ql) {
    int j = blockIdx.x * 256 + threadIdx.x;  // < K_*E_
    float v = DECAY_ * ew[j] + OMD_ * dw[j];
    out_nw[j] = v;
    float nsum = scal[0];
    int k = j >> 5;
    float csk = DECAY_ * cs[k] + OMD_ * cnt[k];
    float denom = (csk + EPS_) / (nsum + (float)K_ * EPS_) * nsum;
    out_nemb[j] = v / denom;
    if (j == 0) {
        out_ql[0] = BETA_ * scal[1] / (float)(B_ * E_ * HW_);
    }
}

extern "C" void kernel_launch(void* const* d_in, const int* in_sizes, int n_in,
                              void* d_out, int out_size, void* d_ws, size_t ws_size,
                              hipStream_t stream) {
    const float* x   = (const float*)d_in[0];
    const float* Wq  = (const float*)d_in[1];
    const float* bq  = (const float*)d_in[2];
    const float* emb = (const float*)d_in[3];
    const float* cs  = (const float*)d_in[4];
    const float* ew  = (const float*)d_in[5];
    float* out = (float*)d_out;
    float* ws  = (float*)d_ws;

    hipMemsetAsync(ws + WS_CNT, 0, (size_t)270338 * sizeof(float), stream);

    k_norm_split<<<K_ / 256, 256, 0, stream>>>(emb,
        (unsigned short*)(ws + WS_EH), (unsigned short*)(ws + WS_EM),
        (unsigned short*)(ws + WS_EL));
    k_score_mfma<<<N_ / 64, 256, 0, stream>>>(x, Wq, bq,
        (const unsigned short*)(ws + WS_EH), (const unsigned short*)(ws + WS_EM),
        (const unsigned short*)(ws + WS_EL),
        (u64*)(ws + WS_P1), (u64*)(ws + WS_P2));
    k_scatter<<<N_ / 64, 256, 0, stream>>>(x, Wq, bq,
        (const u64*)(ws + WS_P1), (const u64*)(ws + WS_P2), emb,
        out + O_ZQ, out + O_IDX, ws + WS_DW, ws + WS_CNT, ws + WS_SCAL);
    k_ema_cs<<<K_ / 256, 256, 0, stream>>>(cs, ws + WS_CNT, out + O_NCS, ws + WS_SCAL);
    k_final<<<(K_ * E_) / 256, 256, 0, stream>>>(ew, ws + WS_DW, cs, ws + WS_CNT,
                                                 ws + WS_SCAL, out + O_NW,
                                                 out + O_NEMB, out + O_QL);
}

// Round 9
// 316.824 us; speedup vs baseline: 2.5028x; 1.5415x over previous
//
#include <hip/hip_runtime.h>

#define B_ 8
#define C_ 256
#define HW_ 4096
#define E_ 32
#define K_ 8192
#define N_ 32768          // B*H*W
#define NCHUNK 2
#define KC_ (K_ / NCHUNK) // 4096
#define STCODES 128
#define NSTAGE (KC_ / STCODES)   // 32

#define DECAY_ 0.99f
#define OMD_   0.01f
#define EPS_   1e-5f
#define BETA_  0.25f

// ---- output layout (fp32 elements, concatenated in reference return order) ----
#define O_ZQ   0          // [B,E,H,W] 1048576
#define O_IDX  1048576    // [B,H,W]   32768
#define O_QL   1081344    // scalar    1
#define O_NEMB 1081345    // [K,E]     262144
#define O_NCS  1343489    // [K]       8192
#define O_NW   1351681    // [K,E]     262144

// ---- workspace layout (float offsets); high-water 794626 floats = 3.18 MB (proven) ----
#define WS_EH   0u        // K*E bf16 hi  [0,      131072)
#define WS_EM   131072u   // K*E bf16 lo  [131072, 262144)
#define WS_PACK 262144u   // 4*N u64: [lvl1 ch0][lvl1 ch1][lvl2 ch0][lvl2 ch1]  [262144,524288)
#define WS_CNT  524288u   // K counts (zeroed)
#define WS_DW   532480u   // K*E dw (zeroed)
#define WS_SCAL 794624u   // [0]=n sum, [1]=qloss sq (zeroed)
// memset span: WS_CNT .. WS_SCAL+2 = 270338 floats

typedef float f32x4 __attribute__((ext_vector_type(4)));
typedef short s16x8 __attribute__((ext_vector_type(8)));
typedef unsigned long long u64;

__device__ __forceinline__ unsigned short f2bf(float f) {
    unsigned u = __float_as_uint(f);
    u = u + 0x7fffu + ((u >> 16) & 1u);
    return (unsigned short)(u >> 16);
}
__device__ __forceinline__ float bf2f(unsigned short h) {
    return __uint_as_float(((unsigned)h) << 16);
}
__device__ __forceinline__ unsigned ford(float f) {
    unsigned u = __float_as_uint(f);
    return (u & 0x80000000u) ? ~u : (u | 0x80000000u);
}

// ---------------- K0: normalize embedding rows + 2-way bf16 split ----------------
__global__ __launch_bounds__(256) void k_norm_split(const float* __restrict__ emb,
                                                    unsigned short* __restrict__ eh,
                                                    unsigned short* __restrict__ em) {
    int k = blockIdx.x * 256 + threadIdx.x;
    if (k >= K_) return;
    const float4* r = (const float4*)(emb + (size_t)k * E_);
    float v[E_];
    float ss = 0.f;
#pragma unroll
    for (int i = 0; i < 8; i++) {
        float4 t = r[i];
        v[i*4+0] = t.x; v[i*4+1] = t.y; v[i*4+2] = t.z; v[i*4+3] = t.w;
        ss += t.x*t.x + t.y*t.y + t.z*t.z + t.w*t.w;
    }
    float inv = 1.0f / fmaxf(sqrtf(ss), 1e-12f);
    unsigned short h1a[E_], h2a[E_];
#pragma unroll
    for (int e = 0; e < E_; e++) {
        float en = v[e] * inv;
        unsigned short h1 = f2bf(en);
        float r1 = en - bf2f(h1);
        unsigned short h2 = f2bf(r1);
        h1a[e] = h1; h2a[e] = h2;
    }
#pragma unroll
    for (int i = 0; i < 4; i++) {
        ((uint4*)(eh + (size_t)k * E_))[i] = ((uint4*)h1a)[i];
        ((uint4*)(em + (size_t)k * E_))[i] = ((uint4*)h2a)[i];
    }
}

// ---------------- K1: MFMA score + per-pixel chunk-local top-2 ----------------
// grid (N/64, NCHUNK). Block: 256 thr (4 waves), 64 pixels, half the codebook.
// LDS: [0,16384) staged codes (2 planes x 8KB, frag-order); [32768,40960) zbuf.
__global__ __launch_bounds__(256) void k_score_mfma(const float* __restrict__ x,
                                                    const float* __restrict__ Wq,
                                                    const float* __restrict__ bq,
                                                    const unsigned short* __restrict__ eh,
                                                    const unsigned short* __restrict__ em,
                                                    u64* __restrict__ pack) {
    __shared__ __align__(16) char smem[40960];
    float* wqt  = (float*)smem;                 // phase 1 only (32 KB)
    float* zbuf = (float*)(smem + 32768);

    int tid  = threadIdx.x;
    int lane = tid & 63;
    int w    = tid >> 6;
    int chunk = blockIdx.y;

    // ---- phase 1: z for the block's 64 pixels ----
#pragma unroll
    for (int i = 0; i < 32; i++) {
        int g = i * 256 + tid;        // g = e*256 + c  (Wq is [E,C])
        int e = g >> 8;
        int c = g & 255;
        wqt[c * E_ + e] = Wq[g];
    }
    __syncthreads();
    {
        int lp = tid & 63, eg = tid >> 6;
        int n0 = blockIdx.x * 64 + lp;
        int b  = n0 >> 12, hw = n0 & (HW_ - 1);
        const float* xp = x + (size_t)b * C_ * HW_ + hw;
        float a[8];
#pragma unroll
        for (int j = 0; j < 8; j++) a[j] = 0.f;
#pragma unroll 4
        for (int c = 0; c < C_; c++) {
            float xv = xp[(size_t)c * HW_];
            const float4* wr = (const float4*)(wqt + c * E_ + eg * 8);
            float4 w0 = wr[0], w1 = wr[1];
            a[0] += xv * w0.x; a[1] += xv * w0.y; a[2] += xv * w0.z; a[3] += xv * w0.w;
            a[4] += xv * w1.x; a[5] += xv * w1.y; a[6] += xv * w1.z; a[7] += xv * w1.w;
        }
        float4* zo = (float4*)(zbuf + lp * E_ + eg * 8);
        zo[0] = make_float4(a[0] + bq[eg*8+0], a[1] + bq[eg*8+1],
                            a[2] + bq[eg*8+2], a[3] + bq[eg*8+3]);
        zo[1] = make_float4(a[4] + bq[eg*8+4], a[5] + bq[eg*8+5],
                            a[6] + bq[eg*8+6], a[7] + bq[eg*8+7]);
    }
    __syncthreads();

    // ---- A fragments: z 2-way bf16 split. A[m=lane&15][k=(lane>>4)*8+j] ----
    s16x8 a1, a2;
    {
        int ploc = w * 16 + (lane & 15);
        int e0   = (lane >> 4) * 8;
#pragma unroll
        for (int j = 0; j < 8; j++) {
            float zv = zbuf[ploc * E_ + e0 + j];
            unsigned short h1 = f2bf(zv);
            float r1 = zv - bf2f(h1);
            a1[j] = (short)h1; a2[j] = (short)f2bf(r1);
        }
    }

    float b1s[4], b2s[4];
    int   i1s[4], i2s[4];
#pragma unroll
    for (int j = 0; j < 4; j++) { b1s[j] = -3.0e38f; b2s[j] = -3.0e38f; i1s[j] = 0; i2s[j] = 0; }
    f32x4 zero4 = {0.f, 0.f, 0.f, 0.f};

    const float4* esrc0 = (const float4*)eh;
    const float4* esrc1 = (const float4*)em;
    float4* lds4 = (float4*)smem;

    for (int st = 0; st < NSTAGE; st++) {
        int codebase = chunk * KC_ + st * STCODES;
        // dest-linear staging: wave writes contiguous 1KB b128 blocks (conflict-free);
        // swizzle lives in the source index (dense permuted 1KB per wave -> coalesced).
#pragma unroll
        for (int i = 0; i < 4; i++) {
            int g  = i * 256 + tid;
            int pl = g >> 9;
            int d  = g & 511;
            int ct = d >> 6;
            int q  = (d >> 4) & 3;
            int c  = codebase + ct * 16 + (d & 15);
            const float4* sb = pl ? esrc1 : esrc0;
            lds4[pl * 512 + d] = sb[(size_t)c * 4 + q];
        }
        __syncthreads();

#pragma unroll
        for (int ct = 0; ct < 8; ct += 2) {
            s16x8 b1a = ((const s16x8*)(smem +        ct * 1024))[lane];
            s16x8 b2a = ((const s16x8*)(smem + 8192 + ct * 1024))[lane];
            s16x8 b1b = ((const s16x8*)(smem +        ct * 1024 + 1024))[lane];
            s16x8 b2b = ((const s16x8*)(smem + 8192 + ct * 1024 + 1024))[lane];
            f32x4 acc0 = __builtin_amdgcn_mfma_f32_16x16x32_bf16(a1, b1a, zero4, 0, 0, 0);
            f32x4 acc1 = __builtin_amdgcn_mfma_f32_16x16x32_bf16(a1, b1b, zero4, 0, 0, 0);
            acc0 = __builtin_amdgcn_mfma_f32_16x16x32_bf16(a1, b2a, acc0, 0, 0, 0);
            acc1 = __builtin_amdgcn_mfma_f32_16x16x32_bf16(a1, b2b, acc1, 0, 0, 0);
            acc0 = __builtin_amdgcn_mfma_f32_16x16x32_bf16(a2, b1a, acc0, 0, 0, 0);
            acc1 = __builtin_amdgcn_mfma_f32_16x16x32_bf16(a2, b1b, acc1, 0, 0, 0);
            int k0 = codebase + ct * 16 + (lane & 15);
#pragma unroll
            for (int j = 0; j < 4; j++) {
                float s = acc0[j];
                bool g1 = s > b1s[j];
                bool g2 = s > b2s[j];
                b2s[j] = g1 ? b1s[j] : (g2 ? s  : b2s[j]);
                i2s[j] = g1 ? i1s[j] : (g2 ? k0 : i2s[j]);
                b1s[j] = g1 ? s  : b1s[j];
                i1s[j] = g1 ? k0 : i1s[j];
            }
            int k1 = k0 + 16;
#pragma unroll
            for (int j = 0; j < 4; j++) {
                float s = acc1[j];
                bool g1 = s > b1s[j];
                bool g2 = s > b2s[j];
                b2s[j] = g1 ? b1s[j] : (g2 ? s  : b2s[j]);
                i2s[j] = g1 ? i1s[j] : (g2 ? k1 : i2s[j]);
                b1s[j] = g1 ? s  : b1s[j];
                i1s[j] = g1 ? k1 : i1s[j];
            }
        }
        __syncthreads();
    }

    // ---- butterfly top-2 merge across the 16-lane code groups ----
    u64 pk1[4], pk2[4];
#pragma unroll
    for (int j = 0; j < 4; j++) {
        pk1[j] = ((u64)ford(b1s[j]) << 32) | (unsigned)(K_ - 1 - i1s[j]);
        pk2[j] = ((u64)ford(b2s[j]) << 32) | (unsigned)(K_ - 1 - i2s[j]);
    }
#pragma unroll
    for (int off = 1; off < 16; off <<= 1) {
#pragma unroll
        for (int j = 0; j < 4; j++) {
            u64 o1 = __shfl_xor(pk1[j], off, 64);
            u64 o2 = __shfl_xor(pk2[j], off, 64);
            u64 lo = pk1[j] < o1 ? pk1[j] : o1;
            pk1[j] = pk1[j] > o1 ? pk1[j] : o1;
            u64 hi2 = pk2[j] > o2 ? pk2[j] : o2;
            pk2[j] = lo > hi2 ? lo : hi2;
        }
    }
    if ((lane & 15) == 0) {
        int rowbase = blockIdx.x * 64 + w * 16 + (lane >> 4) * 4;
#pragma unroll
        for (int j = 0; j < 4; j++) {
            pack[(size_t)chunk * N_ + rowbase + j]            = pk1[j];
            pack[(size_t)(2 + chunk) * N_ + rowbase + j]      = pk2[j];
        }
    }
}

// exact round-4-order rescore of one candidate code against z[32] (LDS)
__device__ __forceinline__ float rescore(const float* __restrict__ emb, int k,
                                         const float* zrow) {
    const float4* r = (const float4*)(emb + (size_t)k * E_);
    float4 v[8];
    float ss = 0.f;
#pragma unroll
    for (int i = 0; i < 8; i++) {
        v[i] = r[i];
        ss += v[i].x * v[i].x + v[i].y * v[i].y + v[i].z * v[i].z + v[i].w * v[i].w;
    }
    float inv = 1.0f / fmaxf(sqrtf(ss), 1e-12f);
    const float4* zp = (const float4*)zrow;
    float sx = 0.f, sy = 0.f, sz = 0.f, sw = 0.f;
#pragma unroll
    for (int i = 0; i < 8; i++) {
        float4 e4 = make_float4(v[i].x * inv, v[i].y * inv, v[i].z * inv, v[i].w * inv);
        float4 zr = zp[i];
        sx += zr.x * e4.x; sy += zr.y * e4.y;
        sz += zr.z * e4.z; sw += zr.w * e4.w;
    }
    return (sx + sy) + (sz + sw);
}

// ---------------- K2: recompute z, exact-rescore 4 candidates, gather/scatter ----------------
__global__ __launch_bounds__(256) void k_scatter(const float* __restrict__ x,
                                                 const float* __restrict__ Wq,
                                                 const float* __restrict__ bq,
                                                 const u64* __restrict__ pack,
                                                 const float* __restrict__ emb,
                                                 float* __restrict__ out_zq,
                                                 float* __restrict__ out_idx,
                                                 float* __restrict__ dw,
                                                 float* __restrict__ cnt,
                                                 float* __restrict__ scal) {
    __shared__ float wqt[C_ * E_];     // 32 KB
    __shared__ float zbuf[64 * E_];    // 8 KB
    __shared__ int   idxs_s[64];
    int tid = threadIdx.x;
#pragma unroll
    for (int i = 0; i < 32; i++) {
        int g = i * 256 + tid;
        int e = g >> 8;
        int c = g & 255;
        wqt[c * E_ + e] = Wq[g];
    }
    __syncthreads();

    int lp = tid & 63, eg = tid >> 6;
    int n  = blockIdx.x * 64 + lp;
    int b  = n >> 12, hw = n & (HW_ - 1);
    const float* xp = x + (size_t)b * C_ * HW_ + hw;

    float a[8];
#pragma unroll
    for (int j = 0; j < 8; j++) a[j] = 0.f;
#pragma unroll 4
    for (int c = 0; c < C_; c++) {
        float xv = xp[(size_t)c * HW_];
        const float4* wr = (const float4*)(wqt + c * E_ + eg * 8);
        float4 w0 = wr[0], w1 = wr[1];
        a[0] += xv * w0.x; a[1] += xv * w0.y; a[2] += xv * w0.z; a[3] += xv * w0.w;
        a[4] += xv * w1.x; a[5] += xv * w1.y; a[6] += xv * w1.z; a[7] += xv * w1.w;
    }
#pragma unroll
    for (int j = 0; j < 8; j++) a[j] += bq[eg * 8 + j];
#pragma unroll
    for (int j = 0; j < 8; j++) zbuf[lp * E_ + eg * 8 + j] = a[j];
    __syncthreads();

    if (tid < 64) {
        int nn = blockIdx.x * 64 + tid;
        int kc[4];
#pragma unroll
        for (int j = 0; j < 4; j++) {
            int ki = K_ - 1 - (int)(unsigned)(pack[(size_t)j * N_ + nn] & 0xffffffffu);
            kc[j] = ki < 0 ? 0 : (ki > K_ - 1 ? K_ - 1 : ki);
        }
        // sort 4 ascending (so strict > picks lowest index on exact ties)
        int t;
#define CSWAP(p, q) if (kc[p] > kc[q]) { t = kc[p]; kc[p] = kc[q]; kc[q] = t; }
        CSWAP(0, 1) CSWAP(2, 3) CSWAP(0, 2) CSWAP(1, 3) CSWAP(1, 2)
#undef CSWAP
        const float* zrow = zbuf + tid * E_;
        float bs = -3.0e38f;
        int   bi = kc[0];
#pragma unroll
        for (int j = 0; j < 4; j++) {
            float s = rescore(emb, kc[j], zrow);
            if (s > bs) { bs = s; bi = kc[j]; }
        }
        idxs_s[tid] = bi;
        out_idx[nn] = (float)bi;
    }
    __syncthreads();

    int idx = idxs_s[lp];
    const float* er = emb + (size_t)idx * E_ + eg * 8;
    float* o = out_zq + (size_t)b * E_ * HW_ + (size_t)(eg * 8) * HW_ + hw;

    float sq = 0.f;
#pragma unroll
    for (int j = 0; j < 8; j++) {
        float zv = a[j];
        float qf = er[j];
        float d = qf - zv;
        sq += d * d;
        o[(size_t)j * HW_] = qf;
        atomicAdd(dw + (size_t)idx * E_ + eg * 8 + j, zv);
    }
    if (eg == 0) atomicAdd(cnt + idx, 1.0f);

#pragma unroll
    for (int off = 32; off > 0; off >>= 1) sq += __shfl_down(sq, off);
    __shared__ float red[4];
    int lane = tid & 63, wid = tid >> 6;
    if (lane == 0) red[wid] = sq;
    __syncthreads();
    if (tid == 0) atomicAdd(scal + 1, red[0] + red[1] + red[2] + red[3]);
}

// ---------------- K3: EMA cluster size + n reduction ----------------
__global__ __launch_bounds__(256) void k_ema_cs(const float* __restrict__ cs,
                                                const float* __restrict__ cnt,
                                                float* __restrict__ out_ncs,
                                                float* __restrict__ scal) {
    int tid = threadIdx.x;
    int k = blockIdx.x * 256 + tid;
    float v = DECAY_ * cs[k] + OMD_ * cnt[k];
    out_ncs[k] = v;

    float s = v;
#pragma unroll
    for (int off = 32; off > 0; off >>= 1) s += __shfl_down(s, off);
    __shared__ float red[4];
    int lane = tid & 63, wid = tid >> 6;
    if (lane == 0) red[wid] = s;
    __syncthreads();
    if (tid == 0) atomicAdd(scal + 0, red[0] + red[1] + red[2] + red[3]);
}

// ---------------- K4: new_w + smoothed division + qloss ----------------
__global__ __launch_bounds__(256) void k_final(const float* __restrict__ ew,
                                               const float* __restrict__ dw,
                                               const float* __restrict__ cs,
                                               const float* __restrict__ cnt,
                                               const float* __restrict__ scal,
                                               float* __restrict__ out_nw,
                                               float* __restrict__ out_nemb,
                                               float* __restrict__ out_ql) {
    int j = blockIdx.x * 256 + threadIdx.x;  // < K_*E_
    float v = DECAY_ * ew[j] + OMD_ * dw[j];
    out_nw[j] = v;
    float nsum = scal[0];
    int k = j >> 5;
    float csk = DECAY_ * cs[k] + OMD_ * cnt[k];
    float denom = (csk + EPS_) / (nsum + (float)K_ * EPS_) * nsum;
    out_nemb[j] = v / denom;
    if (j == 0) {
        out_ql[0] = BETA_ * scal[1] / (float)(B_ * E_ * HW_);
    }
}

extern "C" void kernel_launch(void* const* d_in, const int* in_sizes, int n_in,
                              void* d_out, int out_size, void* d_ws, size_t ws_size,
                              hipStream_t stream) {
    const float* x   = (const float*)d_in[0];
    const float* Wq  = (const float*)d_in[1];
    const float* bq  = (const float*)d_in[2];
    const float* emb = (const float*)d_in[3];
    const float* cs  = (const float*)d_in[4];
    const float* ew  = (const float*)d_in[5];
    float* out = (float*)d_out;
    float* ws  = (float*)d_ws;

    hipMemsetAsync(ws + WS_CNT, 0, (size_t)270338 * sizeof(float), stream);

    k_norm_split<<<K_ / 256, 256, 0, stream>>>(emb,
        (unsigned short*)(ws + WS_EH), (unsigned short*)(ws + WS_EM));
    k_score_mfma<<<dim3(N_ / 64, NCHUNK), 256, 0, stream>>>(x, Wq, bq,
        (const unsigned short*)(ws + WS_EH), (const unsigned short*)(ws + WS_EM),
        (u64*)(ws + WS_PACK));
    k_scatter<<<N_ / 64, 256, 0, stream>>>(x, Wq, bq,
        (const u64*)(ws + WS_PACK), emb,
        out + O_ZQ, out + O_IDX, ws + WS_DW, ws + WS_CNT, ws + WS_SCAL);
    k_ema_cs<<<K_ / 256, 256, 0, stream>>>(cs, ws + WS_CNT, out + O_NCS, ws + WS_SCAL);
    k_final<<<(K_ * E_) / 256, 256, 0, stream>>>(ew, ws + WS_DW, cs, ws + WS_CNT,
                                                 ws + WS_SCAL, out + O_NW,
                                                 out + O_NEMB, out + O_QL);
}

// Round 10
// 287.371 us; speedup vs baseline: 2.7593x; 1.1025x over previous
//
#include <hip/hip_runtime.h>

#define B_ 8
#define C_ 256
#define HW_ 4096
#define E_ 32
#define K_ 8192
#define N_ 32768          // B*H*W
#define NCHUNK 2
#define KC_ (K_ / NCHUNK) // 4096
#define STCODES 128
#define NSTAGE (KC_ / STCODES)   // 32

#define DECAY_ 0.99f
#define OMD_   0.01f
#define EPS_   1e-5f
#define BETA_  0.25f

// ---- output layout (fp32 elements, concatenated in reference return order) ----
#define O_ZQ   0          // [B,E,H,W] 1048576
#define O_IDX  1048576    // [B,H,W]   32768
#define O_QL   1081344    // scalar    1
#define O_NEMB 1081345    // [K,E]     262144
#define O_NCS  1343489    // [K]       8192
#define O_NW   1351681    // [K,E]     262144

// ---- workspace layout (float offsets); high-water 663554 floats = 2.65 MB (proven 3.18) ----
// eh/em are PRE-SWIZZLED into MFMA-frag order: uint4 chunk (tile t, q, c15) at t*64+q*16+c15.
#define WS_EH   0u        // K*E bf16 hi  [0,      131072)
#define WS_EM   131072u   // K*E bf16 lo  [131072, 262144)
#define WS_PACK 262144u   // 2 chunks x N int2 (packed top1,top2)  [262144, 393216)
#define WS_CNT  393216u   // K counts (zeroed)
#define WS_DW   401408u   // K*E dw (zeroed)
#define WS_SCAL 663552u   // [0]=n sum, [1]=qloss sq (zeroed)
// memset span: WS_CNT .. WS_SCAL+2 = 270338 floats

typedef float f32x4 __attribute__((ext_vector_type(4)));
typedef short s16x8 __attribute__((ext_vector_type(8)));
typedef unsigned long long u64;

__device__ __forceinline__ unsigned short f2bf(float f) {
    unsigned u = __float_as_uint(f);
    u = u + 0x7fffu + ((u >> 16) & 1u);
    return (unsigned short)(u >> 16);
}
__device__ __forceinline__ float bf2f(unsigned short h) {
    return __uint_as_float(((unsigned)h) << 16);
}
__device__ __forceinline__ unsigned ford(float f) {
    unsigned u = __float_as_uint(f);
    return (u & 0x80000000u) ? ~u : (u | 0x80000000u);
}
__device__ __forceinline__ int imax(int a, int b) { return a > b ? a : b; }
__device__ __forceinline__ int imin(int a, int b) { return a < b ? a : b; }

// async global->LDS, 16B per lane (dest must be wave-uniform base + lane*16 — it is)
__device__ __forceinline__ void gload_lds16(const void* g, void* l) {
    __builtin_amdgcn_global_load_lds(
        (const __attribute__((address_space(1))) unsigned int*)g,
        (__attribute__((address_space(3))) unsigned int*)l, 16, 0, 0);
}

// ---------------- K0: normalize rows + 2-way bf16 split, stored frag-swizzled ----------------
__global__ __launch_bounds__(256) void k_norm_split(const float* __restrict__ emb,
                                                    uint4* __restrict__ eh16,
                                                    uint4* __restrict__ em16) {
    int k = blockIdx.x * 256 + threadIdx.x;
    if (k >= K_) return;
    const float4* r = (const float4*)(emb + (size_t)k * E_);
    float v[E_];
    float ss = 0.f;
#pragma unroll
    for (int i = 0; i < 8; i++) {
        float4 t = r[i];
        v[i*4+0] = t.x; v[i*4+1] = t.y; v[i*4+2] = t.z; v[i*4+3] = t.w;
        ss += t.x*t.x + t.y*t.y + t.z*t.z + t.w*t.w;
    }
    float inv = 1.0f / fmaxf(sqrtf(ss), 1e-12f);
    unsigned short h1a[E_], h2a[E_];
#pragma unroll
    for (int e = 0; e < E_; e++) {
        float en = v[e] * inv;
        unsigned short h1 = f2bf(en);
        float r1 = en - bf2f(h1);
        h1a[e] = h1; h2a[e] = f2bf(r1);
    }
    int t = k >> 4, c15 = k & 15;
#pragma unroll
    for (int i = 0; i < 4; i++) {   // quad i = k-elements 8i..8i+7
        eh16[t * 64 + i * 16 + c15] = ((uint4*)h1a)[i];
        em16[t * 64 + i * 16 + c15] = ((uint4*)h2a)[i];
    }
}

// ---------------- K1: MFMA score + int-packed per-pixel chunk-local top-2 ----------------
// grid (N/64, NCHUNK), 256 thr (4 waves), 64 pixels, half codebook per block.
// LDS: [0,16384) buf0, [16384,32768) buf1 (stage: 8KB hi + 8KB lo), [32768,40960) zbuf.
__global__ __launch_bounds__(256) void k_score_mfma(const float* __restrict__ x,
                                                    const float* __restrict__ Wq,
                                                    const float* __restrict__ bq,
                                                    const char* __restrict__ ehb,
                                                    const char* __restrict__ emb_b,
                                                    int2* __restrict__ pk2) {
    __shared__ __align__(16) char smem[40960];
    float* wqt  = (float*)smem;                 // phase 1 only (32 KB)
    float* zbuf = (float*)(smem + 32768);

    int tid  = threadIdx.x;
    int lane = tid & 63;
    int w    = tid >> 6;
    int chunk = blockIdx.y;

    // ---- phase 1: z for the block's 64 pixels ----
#pragma unroll
    for (int i = 0; i < 32; i++) {
        int g = i * 256 + tid;        // g = e*256 + c  (Wq is [E,C])
        int e = g >> 8;
        int c = g & 255;
        wqt[c * E_ + e] = Wq[g];
    }
    __syncthreads();
    {
        int lp = tid & 63, eg = tid >> 6;
        int n0 = blockIdx.x * 64 + lp;
        int b  = n0 >> 12, hw = n0 & (HW_ - 1);
        const float* xp = x + (size_t)b * C_ * HW_ + hw;
        float a[8];
#pragma unroll
        for (int j = 0; j < 8; j++) a[j] = 0.f;
#pragma unroll 4
        for (int c = 0; c < C_; c++) {
            float xv = xp[(size_t)c * HW_];
            const float4* wr = (const float4*)(wqt + c * E_ + eg * 8);
            float4 w0 = wr[0], w1 = wr[1];
            a[0] += xv * w0.x; a[1] += xv * w0.y; a[2] += xv * w0.z; a[3] += xv * w0.w;
            a[4] += xv * w1.x; a[5] += xv * w1.y; a[6] += xv * w1.z; a[7] += xv * w1.w;
        }
        float4* zo = (float4*)(zbuf + lp * E_ + eg * 8);
        zo[0] = make_float4(a[0] + bq[eg*8+0], a[1] + bq[eg*8+1],
                            a[2] + bq[eg*8+2], a[3] + bq[eg*8+3]);
        zo[1] = make_float4(a[4] + bq[eg*8+4], a[5] + bq[eg*8+5],
                            a[6] + bq[eg*8+6], a[7] + bq[eg*8+7]);
    }
    __syncthreads();

    // ---- A fragments: z 2-way bf16 split. A[m=lane&15][k=(lane>>4)*8+j] ----
    s16x8 a1, a2;
    {
        int ploc = w * 16 + (lane & 15);
        int e0   = (lane >> 4) * 8;
#pragma unroll
        for (int j = 0; j < 8; j++) {
            float zv = zbuf[ploc * E_ + e0 + j];
            unsigned short h1 = f2bf(zv);
            float r1 = zv - bf2f(h1);
            a1[j] = (short)h1; a2[j] = (short)f2bf(r1);
        }
    }

    // staging source pointers (pre-swizzled planes are stage-linear)
    const char* srcp[4];
#pragma unroll
    for (int i = 0; i < 4; i++) {
        int d = i * 256 + tid;
        int pl = d >> 9, dd = d & 511;
        srcp[i] = (pl ? emb_b : ehb) + (size_t)chunk * 262144 + dd * 16;
    }

    // prologue: stage 0 -> buf0
#pragma unroll
    for (int i = 0; i < 4; i++)
        gload_lds16(srcp[i], smem + (i * 256 + tid) * 16);
    __syncthreads();

    int rbase = 8191 - chunk * KC_ - (lane & 15);
    int bq1[4], bq2[4];
#pragma unroll
    for (int j = 0; j < 4; j++) { bq1[j] = (int)0x80000000; bq2[j] = (int)0x80000000; }
    f32x4 zero4 = {0.f, 0.f, 0.f, 0.f};

    for (int st = 0; st < NSTAGE; st++) {
        if (st + 1 < NSTAGE) {
            char* dst = smem + ((st + 1) & 1) * 16384;
#pragma unroll
            for (int i = 0; i < 4; i++)
                gload_lds16(srcp[i] + (size_t)(st + 1) * 8192, dst + (i * 256 + tid) * 16);
        }
        const char* cur = smem + (st & 1) * 16384;
        int rst = rbase - st * 128;

#pragma unroll
        for (int ct = 0; ct < 8; ct += 2) {
            s16x8 b1a = ((const s16x8*)(cur +        ct * 1024))[lane];
            s16x8 b2a = ((const s16x8*)(cur + 8192 + ct * 1024))[lane];
            s16x8 b1b = ((const s16x8*)(cur +        ct * 1024 + 1024))[lane];
            s16x8 b2b = ((const s16x8*)(cur + 8192 + ct * 1024 + 1024))[lane];
            f32x4 acc0 = __builtin_amdgcn_mfma_f32_16x16x32_bf16(a1, b1a, zero4, 0, 0, 0);
            f32x4 acc1 = __builtin_amdgcn_mfma_f32_16x16x32_bf16(a1, b1b, zero4, 0, 0, 0);
            acc0 = __builtin_amdgcn_mfma_f32_16x16x32_bf16(a1, b2a, acc0, 0, 0, 0);
            acc1 = __builtin_amdgcn_mfma_f32_16x16x32_bf16(a1, b2b, acc1, 0, 0, 0);
            acc0 = __builtin_amdgcn_mfma_f32_16x16x32_bf16(a2, b1a, acc0, 0, 0, 0);
            acc1 = __builtin_amdgcn_mfma_f32_16x16x32_bf16(a2, b1b, acc1, 0, 0, 0);
            int rA = rst - ct * 16;
            int rB = rA - 16;
#pragma unroll
            for (int j = 0; j < 4; j++) {
                int va = ((int)(acc0[j] * 16384.0f) << 13) | rA;
                int vb = ((int)(acc1[j] * 16384.0f) << 13) | rB;
                int hi = imax(va, vb), lo = imin(va, vb);
                int m  = imin(bq1[j], hi);
                bq1[j] = imax(bq1[j], hi);
                bq2[j] = imax(imax(bq2[j], lo), m);
            }
        }
        __syncthreads();
    }

    // butterfly top-2 merge across 16-lane code groups (int compare; low bits = 8191-idx)
#pragma unroll
    for (int off = 1; off < 16; off <<= 1) {
#pragma unroll
        for (int j = 0; j < 4; j++) {
            int o1 = __shfl_xor(bq1[j], off, 64);
            int o2 = __shfl_xor(bq2[j], off, 64);
            int m  = imin(bq1[j], o1);
            bq1[j] = imax(bq1[j], o1);
            bq2[j] = imax(imax(bq2[j], o2), m);
        }
    }
    if ((lane & 15) == 0) {
        int rowbase = blockIdx.x * 64 + w * 16 + (lane >> 4) * 4;
#pragma unroll
        for (int j = 0; j < 4; j++)
            pk2[(size_t)chunk * N_ + rowbase + j] = make_int2(bq1[j], bq2[j]);
    }
}

// exact round-4-order rescore of one candidate code against z[32]
__device__ __forceinline__ float rescore(const float* __restrict__ emb, int k,
                                         const float* zrow) {
    const float4* r = (const float4*)(emb + (size_t)k * E_);
    float4 v[8];
    float ss = 0.f;
#pragma unroll
    for (int i = 0; i < 8; i++) {
        v[i] = r[i];
        ss += v[i].x * v[i].x + v[i].y * v[i].y + v[i].z * v[i].z + v[i].w * v[i].w;
    }
    float inv = 1.0f / fmaxf(sqrtf(ss), 1e-12f);
    const float4* zp = (const float4*)zrow;
    float sx = 0.f, sy = 0.f, sz = 0.f, sw = 0.f;
#pragma unroll
    for (int i = 0; i < 8; i++) {
        float4 e4 = make_float4(v[i].x * inv, v[i].y * inv, v[i].z * inv, v[i].w * inv);
        float4 zr = zp[i];
        sx += zr.x * e4.x; sy += zr.y * e4.y;
        sz += zr.z * e4.z; sw += zr.w * e4.w;
    }
    return (sx + sy) + (sz + sw);
}

// ---------------- K2: recompute z, rescore 4 candidates (parallel), gather/scatter ----------------
// 512 threads (8 waves), 64 pixels.
__global__ __launch_bounds__(512) void k_scatter(const float* __restrict__ x,
                                                 const float* __restrict__ Wq,
                                                 const float* __restrict__ bq,
                                                 const int2* __restrict__ pk2,
                                                 const float* __restrict__ emb,
                                                 float* __restrict__ out_zq,
                                                 float* __restrict__ out_idx,
                                                 float* __restrict__ dw,
                                                 float* __restrict__ cnt,
                                                 float* __restrict__ scal) {
    __shared__ float wqt[C_ * E_];     // 32 KB
    __shared__ float zbuf[64 * E_];    // 8 KB
    __shared__ int   idxs_s[64];
    __shared__ float red[8];
    int tid = threadIdx.x;
#pragma unroll
    for (int i = 0; i < 16; i++) {
        int g = i * 512 + tid;
        int e = g >> 8;
        int c = g & 255;
        wqt[c * E_ + e] = Wq[g];
    }
    __syncthreads();

    int lp = tid & 63, eg = tid >> 6;   // eg 0..7, 4 e's each
    int n  = blockIdx.x * 64 + lp;
    int b  = n >> 12, hw = n & (HW_ - 1);
    const float* xp = x + (size_t)b * C_ * HW_ + hw;

    float a[4] = {0.f, 0.f, 0.f, 0.f};
#pragma unroll 8
    for (int c = 0; c < C_; c++) {
        float xv = xp[(size_t)c * HW_];
        float4 w0 = *(const float4*)(wqt + c * E_ + eg * 4);
        a[0] += xv * w0.x; a[1] += xv * w0.y; a[2] += xv * w0.z; a[3] += xv * w0.w;
    }
#pragma unroll
    for (int j = 0; j < 4; j++) a[j] += bq[eg * 4 + j];
#pragma unroll
    for (int j = 0; j < 4; j++) zbuf[lp * E_ + eg * 4 + j] = a[j];
    __syncthreads();

    if (tid < 256) {
        int p = tid >> 2, c4 = tid & 3;
        int nn = blockIdx.x * 64 + p;
        int2 ca = pk2[nn], cb = pk2[N_ + nn];
        int raw = (c4 == 0) ? ca.x : (c4 == 1) ? ca.y : (c4 == 2) ? cb.x : cb.y;
        int k = 8191 - (raw & 0x1fff);
        k = k < 0 ? 0 : (k > K_ - 1 ? K_ - 1 : k);
        float s = rescore(emb, k, zbuf + p * E_);
        u64 pkd = ((u64)ford(s) << 32) | (unsigned)(K_ - 1 - k);  // ties -> lowest idx
        u64 o = __shfl_xor(pkd, 1, 64); pkd = pkd > o ? pkd : o;
        o = __shfl_xor(pkd, 2, 64);     pkd = pkd > o ? pkd : o;
        if (c4 == 0) {
            int bi = K_ - 1 - (int)(unsigned)(pkd & 0xffffffffu);
            idxs_s[p] = bi;
            out_idx[nn] = (float)bi;
        }
    }
    __syncthreads();

    int idx = idxs_s[lp];
    const float* er = emb + (size_t)idx * E_ + eg * 4;
    float* o = out_zq + (size_t)b * E_ * HW_ + (size_t)(eg * 4) * HW_ + hw;

    float sq = 0.f;
#pragma unroll
    for (int j = 0; j < 4; j++) {
        float zv = a[j];
        float qf = er[j];
        float d = qf - zv;
        sq += d * d;
        o[(size_t)j * HW_] = qf;
        atomicAdd(dw + (size_t)idx * E_ + eg * 4 + j, zv);
    }
    if (eg == 0) atomicAdd(cnt + idx, 1.0f);

#pragma unroll
    for (int off = 32; off > 0; off >>= 1) sq += __shfl_down(sq, off);
    int lane = tid & 63, wid = tid >> 6;
    if (lane == 0) red[wid] = sq;
    __syncthreads();
    if (tid == 0) {
        float t = 0.f;
#pragma unroll
        for (int i = 0; i < 8; i++) t += red[i];
        atomicAdd(scal + 1, t);
    }
}

// ---------------- K3: EMA cluster size + n reduction ----------------
__global__ __launch_bounds__(256) void k_ema_cs(const float* __restrict__ cs,
                                                const float* __restrict__ cnt,
                                                float* __restrict__ out_ncs,
                                                float* __restrict__ scal) {
    int tid = threadIdx.x;
    int k = blockIdx.x * 256 + tid;
    float v = DECAY_ * cs[k] + OMD_ * cnt[k];
    out_ncs[k] = v;

    float s = v;
#pragma unroll
    for (int off = 32; off > 0; off >>= 1) s += __shfl_down(s, off);
    __shared__ float red[4];
    int lane = tid & 63, wid = tid >> 6;
    if (lane == 0) red[wid] = s;
    __syncthreads();
    if (tid == 0) atomicAdd(scal + 0, red[0] + red[1] + red[2] + red[3]);
}

// ---------------- K4: new_w + smoothed division + qloss ----------------
__global__ __launch_bounds__(256) void k_final(const float* __restrict__ ew,
                                               const float* __restrict__ dw,
                                               const float* __restrict__ cs,
                                               const float* __restrict__ cnt,
                                               const float* __restrict__ scal,
                                               float* __restrict__ out_nw,
                                               float* __restrict__ out_nemb,
                                               float* __restrict__ out_ql) {
    int j = blockIdx.x * 256 + threadIdx.x;  // < K_*E_
    float v = DECAY_ * ew[j] + OMD_ * dw[j];
    out_nw[j] = v;
    float nsum = scal[0];
    int k = j >> 5;
    float csk = DECAY_ * cs[k] + OMD_ * cnt[k];
    float denom = (csk + EPS_) / (nsum + (float)K_ * EPS_) * nsum;
    out_nemb[j] = v / denom;
    if (j == 0) {
        out_ql[0] = BETA_ * scal[1] / (float)(B_ * E_ * HW_);
    }
}

extern "C" void kernel_launch(void* const* d_in, const int* in_sizes, int n_in,
                              void* d_out, int out_size, void* d_ws, size_t ws_size,
                              hipStream_t stream) {
    const float* x   = (const float*)d_in[0];
    const float* Wq  = (const float*)d_in[1];
    const float* bq  = (const float*)d_in[2];
    const float* emb = (const float*)d_in[3];
    const float* cs  = (const float*)d_in[4];
    const float* ew  = (const float*)d_in[5];
    float* out = (float*)d_out;
    float* ws  = (float*)d_ws;

    hipMemsetAsync(ws + WS_CNT, 0, (size_t)270338 * sizeof(float), stream);

    k_norm_split<<<K_ / 256, 256, 0, stream>>>(emb,
        (uint4*)(ws + WS_EH), (uint4*)(ws + WS_EM));
    k_score_mfma<<<dim3(N_ / 64, NCHUNK), 256, 0, stream>>>(x, Wq, bq,
        (const char*)(ws + WS_EH), (const char*)(ws + WS_EM),
        (int2*)(ws + WS_PACK));
    k_scatter<<<N_ / 64, 512, 0, stream>>>(x, Wq, bq,
        (const int2*)(ws + WS_PACK), emb,
        out + O_ZQ, out + O_IDX, ws + WS_DW, ws + WS_CNT, ws + WS_SCAL);
    k_ema_cs<<<K_ / 256, 256, 0, stream>>>(cs, ws + WS_CNT, out + O_NCS, ws + WS_SCAL);
    k_final<<<(K_ * E_) / 256, 256, 0, stream>>>(ew, ws + WS_DW, cs, ws + WS_CNT,
                                                 ws + WS_SCAL, out + O_NW,
                                                 out + O_NEMB, out + O_QL);
}